// Round 17
// baseline (425.548 us; speedup 1.0000x reference)
//
#include <hip/hip_runtime.h>
#include <hip/hip_bf16.h>

#define IN_CHN 256
#define OUT_CHN 256
#define REL_DIM 1536
#define HIDN 512

using short8 = __attribute__((ext_vector_type(8))) short;
using f32x4  = __attribute__((ext_vector_type(4))) float;

__device__ __forceinline__ float bf2f(short s) {
    union { unsigned u; float f; } v;
    v.u = ((unsigned)(unsigned short)s) << 16;
    return v.f;
}
__device__ __forceinline__ unsigned cvt_pk_bf16(float a, float b) {
    unsigned r;
    asm("v_cvt_pk_bf16_f32 %0, %1, %2" : "=v"(r) : "v"(a), "v"(b));
    return r;
}
__device__ __forceinline__ unsigned short f2bf_s(float f) {
    union { float f; unsigned u; } v; v.f = f;
    unsigned u = v.u + 0x7FFFu + ((v.u >> 16) & 1u);
    return (unsigned short)(u >> 16);
}

// ---------------- prep: transpose+cast weights to bf16 ----------------
__global__ void k_prep_w(const float* __restrict__ W1, const float* __restrict__ Ws,
                         const float* __restrict__ W2,
                         unsigned short* __restrict__ Bt, unsigned short* __restrict__ W2t,
                         unsigned short* __restrict__ Wst)
{
    int idx = blockIdx.x * 256 + threadIdx.x;
    const int n1 = HIDN * IN_CHN;
    const int n2 = OUT_CHN * HIDN;
    const int n3 = OUT_CHN * IN_CHN;
    if (idx < n1) {
        int j = idx >> 8, k = idx & 255;
        Bt[idx] = f2bf_s(W1[(size_t)k * HIDN + j]);
    } else if (idx < n1 + n2) {
        int t = idx - n1;
        int j = t >> 9, k = t & 511;
        W2t[t] = f2bf_s(W2[(size_t)k * OUT_CHN + j]);
    } else if (idx < n1 + n2 + n3) {
        int t = idx - n1 - n2;
        int j = t >> 8, k = t & 255;
        Wst[t] = f2bf_s(Ws[(size_t)k * OUT_CHN + j]);
    }
}

// ---------------- R[r] = rel[r] @ W1_bot + b1 (bf16 out) ----------------
__global__ __launch_bounds__(512) void k_rel(const float* __restrict__ rel,
                                             const float* __restrict__ W1,
                                             const float* __restrict__ b1,
                                             unsigned short* __restrict__ Rb)
{
    __shared__ float s[REL_DIM];
    const int r = blockIdx.x;
    for (int i = threadIdx.x; i < REL_DIM; i += 512)
        s[i] = rel[(size_t)r * REL_DIM + i];
    __syncthreads();
    const int j = threadIdx.x;
    float acc = b1[j];
    const float* wp = W1 + (size_t)IN_CHN * HIDN + j;
#pragma unroll 8
    for (int k = 0; k < REL_DIM; ++k)
        acc = fmaf(s[k], wp[(size_t)k * HIDN], acc);
    Rb[r * HIDN + j] = f2bf_s(acc);
}

// ---------------- node GEMM: X1 = bf16(x) @ Bt^T  (single pass, R11/R16-proven body) ----------------
__global__ __launch_bounds__(512) void k_node(const float* __restrict__ x,
                                              const unsigned short* __restrict__ Bt,
                                              unsigned short* __restrict__ X1, int N)
{
    __shared__ unsigned short Alds[64][72];   // 9.2 KB, +8-short pad
    const int row0 = blockIdx.x * 64;
    const int tid = threadIdx.x;
    const int w = tid >> 6, l = tid & 63;
    const int l15 = l & 15, lg = l >> 4;
    const int colw = w * 64;

    // staging role: thread t covers row t>>3, 8 f32 elements at (t&7)*8
    const int srow = tid >> 3;
    int srowg = row0 + srow; if (srowg >= N) srowg = N - 1;
    const int sc = (tid & 7) * 8;
    const float* xsrc = x + (size_t)srowg * IN_CHN + sc;
    unsigned short* sdst = &Alds[srow][sc];

    const unsigned short* bp[4];
#pragma unroll
    for (int cf = 0; cf < 4; ++cf)
        bp[cf] = Bt + (size_t)(colw + 16 * cf + l15) * IN_CHN + 8 * lg;
    const unsigned short* ard[4];
#pragma unroll
    for (int rf = 0; rf < 4; ++rf)
        ard[rf] = &Alds[16 * rf + l15][lg * 8];

    f32x4 acc[4][4] = {};

    {   // stage tile 0
        float4 g0 = *(const float4*)(xsrc + 0);
        float4 g1 = *(const float4*)(xsrc + 4);
        union { short8 s; unsigned u[4]; } p;
        p.u[0] = cvt_pk_bf16(g0.x, g0.y); p.u[1] = cvt_pk_bf16(g0.z, g0.w);
        p.u[2] = cvt_pk_bf16(g1.x, g1.y); p.u[3] = cvt_pk_bf16(g1.z, g1.w);
        *(short8*)sdst = p.s;
    }
    __syncthreads();
    for (int t = 0; t < 4; ++t) {             // K=256 as 4 tiles of BK=64
        float4 g0, g1;
        if (t + 1 < 4) {                      // issue next tile's loads early
            g0 = *(const float4*)(xsrc + (t + 1) * 64);
            g1 = *(const float4*)(xsrc + (t + 1) * 64 + 4);
        }
#pragma unroll
        for (int kk = 0; kk < 2; ++kk) {
            short8 a[4], b[4];
#pragma unroll
            for (int rf = 0; rf < 4; ++rf)
                a[rf] = *(const short8*)(ard[rf] + kk * 32);
#pragma unroll
            for (int cf = 0; cf < 4; ++cf)
                b[cf] = *(const short8*)(bp[cf] + t * 64 + kk * 32);
#pragma unroll
            for (int rf = 0; rf < 4; ++rf)
#pragma unroll
                for (int cf = 0; cf < 4; ++cf)
                    acc[rf][cf] = __builtin_amdgcn_mfma_f32_16x16x32_bf16(a[rf], b[cf], acc[rf][cf], 0, 0, 0);
        }
        __syncthreads();
        if (t + 1 < 4) {
            union { short8 s; unsigned u[4]; } p;
            p.u[0] = cvt_pk_bf16(g0.x, g0.y); p.u[1] = cvt_pk_bf16(g0.z, g0.w);
            p.u[2] = cvt_pk_bf16(g1.x, g1.y); p.u[3] = cvt_pk_bf16(g1.z, g1.w);
            *(short8*)sdst = p.s;
            __syncthreads();
        }
    }

#pragma unroll
    for (int rf = 0; rf < 4; ++rf) {
#pragma unroll
        for (int cf = 0; cf < 4; ++cf) {
            int col = colw + 16 * cf + l15;
#pragma unroll
            for (int r = 0; r < 4; ++r) {
                int row = row0 + 16 * rf + 4 * lg + r;
                if (row >= N) continue;
                X1[(size_t)row * HIDN + col] = f2bf_s(acc[rf][cf][r]);
            }
        }
    }
}

// ---------------- CSR build ----------------
__global__ void k_hist(const int* __restrict__ ei, int* __restrict__ cnt, int E)
{
    int e = blockIdx.x * 256 + threadIdx.x;
    if (e < E) atomicAdd(&cnt[ei[E + e]], 1);
}

__global__ __launch_bounds__(512) void k_scan1(const int* __restrict__ cnt, int* __restrict__ offs,
                                               int* __restrict__ bsum, int N)
{
    __shared__ int s[512];
    int t = threadIdx.x;
    int i = blockIdx.x * 512 + t;
    int v = (i < N) ? cnt[i] : 0;
    s[t] = v;
    __syncthreads();
    for (int d = 1; d < 512; d <<= 1) {
        int a = (t >= d) ? s[t - d] : 0;
        __syncthreads();
        s[t] += a;
        __syncthreads();
    }
    if (i < N) offs[i] = s[t] - v;
    if (t == 511) bsum[blockIdx.x] = s[511];
}

__global__ __launch_bounds__(512) void k_scan2(int* __restrict__ bsum, int NB)
{
    __shared__ int s[512];
    int t = threadIdx.x;
    if (t < NB) s[t] = bsum[t];
    __syncthreads();
    if (t == 0) {
        int run = 0;
        for (int j = 0; j < NB; ++j) { int v = s[j]; s[j] = run; run += v; }
    }
    __syncthreads();
    if (t < NB) bsum[t] = s[t];
}

__global__ void k_scan3(int* __restrict__ offs, const int* __restrict__ bsum,
                        int* __restrict__ cursor, int N, int E)
{
    int i = blockIdx.x * 256 + threadIdx.x;
    if (i < N) {
        int v = offs[i] + bsum[i >> 9];
        offs[i] = v;
        cursor[i] = v;
    }
    if (i == 0) offs[N] = E;
}

__global__ void k_scatter(const int* __restrict__ ei, const int* __restrict__ et,
                          int* __restrict__ cursor, int* __restrict__ eperm, int E)
{
    int e = blockIdx.x * 256 + threadIdx.x;
    if (e < E) {
        int d = ei[E + e];
        int pos = atomicAdd(&cursor[d], 1);
        eperm[pos] = ei[e] | (et[e] << 20);   // src | etype<<20
    }
}

// ---------------- gather: Hagg[g] = sum_{e->g} relu(X1[src]+R[et]) (bf16) ----------------
// One wave per node; 8-wide edge batching (16 outstanding gather loads/wave).
// launch_bounds (256,4): reg cap 128 -> no spill with 64 VGPR of batch data.
__global__ __launch_bounds__(256, 4) void k_gather(const int* __restrict__ offs,
                                                   const int* __restrict__ eperm,
                                                   const unsigned short* __restrict__ X1,
                                                   const unsigned short* __restrict__ Rb,
                                                   unsigned short* __restrict__ Hagg, int N)
{
    const int g = (blockIdx.x * 256 + threadIdx.x) >> 6;   // global wave id = node
    const int l = threadIdx.x & 63;
    if (g >= N) return;
    const int o0 = offs[g], o1 = offs[g + 1];
    const int deg = o1 - o0;
    float a8[8] = {};
    for (int base = 0; base < deg; base += 64) {
        const int nk = min(64, deg - base);
        int pv = eperm[o0 + base + (l < nk ? l : nk - 1)];
        for (int e = 0; e < nk; e += 8) {
            int pvk[8];
#pragma unroll
            for (int k2 = 0; k2 < 8; ++k2)
                pvk[k2] = __shfl(pv, e + k2);
            short8 xa[8], ra[8];
#pragma unroll
            for (int k2 = 0; k2 < 8; ++k2) {
                if (e + k2 < nk) {
                    xa[k2] = *(const short8*)(X1 + (size_t)(pvk[k2] & 0xFFFFF) * HIDN + l * 8);
                    ra[k2] = *(const short8*)(Rb + (pvk[k2] >> 20) * HIDN + l * 8);
                }
            }
#pragma unroll
            for (int k2 = 0; k2 < 8; ++k2) {
                if (e + k2 < nk) {
#pragma unroll
                    for (int j = 0; j < 8; ++j)
                        a8[j] += fmaxf(bf2f(xa[k2][j]) + bf2f(ra[k2][j]), 0.f);
                }
            }
        }
    }
    union { short8 s; unsigned u[4]; } pk;
    pk.u[0] = cvt_pk_bf16(a8[0], a8[1]);
    pk.u[1] = cvt_pk_bf16(a8[2], a8[3]);
    pk.u[2] = cvt_pk_bf16(a8[4], a8[5]);
    pk.u[3] = cvt_pk_bf16(a8[6], a8[7]);
    *(short8*)(Hagg + (size_t)g * HIDN + l * 8) = pk.s;
}

// ---------------- out GEMM: out = Hagg@W2t + x@Wst + deg*b2 + bs -> LN -> ReLU ----------------
// R13-proven 64-row body: phase A = 4 tiles of BK=128, phase B = 4 tiles of BK=64.
// Row stride 136 shorts (proven bank signature). Hagg aliases d_out.
__global__ __launch_bounds__(256) void k_out(const unsigned short* __restrict__ Hagg,
                                             const unsigned short* __restrict__ W2t,
                                             const unsigned short* __restrict__ Wst,
                                             const float* __restrict__ x,
                                             const int* __restrict__ offs,
                                             const float* __restrict__ b2,
                                             const float* __restrict__ bs,
                                             const float* __restrict__ gamma,
                                             const float* __restrict__ beta,
                                             float* __restrict__ out, int N)
{
    __shared__ unsigned short Alds[64][136];  // 17.4 KB, +8-short pad
    __shared__ float sdeg[64];
    __shared__ float sred[4][64], sqred[4][64];
    const int row0 = blockIdx.x * 64;
    const int tid = threadIdx.x;
    const int w = tid >> 6, l = tid & 63;
    const int l15 = l & 15, lg = l >> 4;
    const int colw = w * 64;

    if (tid < 64) {
        int g = row0 + tid;
        if (g >= N) g = N - 1;
        sdeg[tid] = (float)(offs[g + 1] - offs[g]);
    }

    const int srow = tid >> 2;
    int srowg = row0 + srow; if (srowg >= N) srowg = N - 1;
    // phase A staging: 32 shorts/thread at (t&3)*32
    const int scA = (tid & 3) * 32;
    const unsigned short* hsrc = Hagg + (size_t)srowg * HIDN + scA;
    unsigned short* sdstA = &Alds[srow][scA];
    // phase B staging: 16 shorts/thread at (t&3)*16 (R10 pattern)
    const int scB = (tid & 3) * 16;
    const float* xsrc = x + (size_t)srowg * IN_CHN + scB;
    unsigned short* sdstB0 = &Alds[srow][scB];
    unsigned short* sdstB1 = &Alds[srow][scB + 8];

    const unsigned short* bp[4];
    const unsigned short* sp[4];
#pragma unroll
    for (int cf = 0; cf < 4; ++cf) {
        bp[cf] = W2t + (size_t)(colw + 16 * cf + l15) * HIDN + 8 * lg;
        sp[cf] = Wst + (size_t)(colw + 16 * cf + l15) * IN_CHN + 8 * lg;
    }
    const unsigned short* ard[4];
#pragma unroll
    for (int rf = 0; rf < 4; ++rf)
        ard[rf] = &Alds[16 * rf + l15][lg * 8];

    f32x4 acc[4][4] = {};
    short8 st0, st1, st2, st3;

    // ================= phase A: Hagg @ W2t, 4 tiles of BK=128 =================
    st0 = *(const short8*)(hsrc + 0);
    st1 = *(const short8*)(hsrc + 8);
    st2 = *(const short8*)(hsrc + 16);
    st3 = *(const short8*)(hsrc + 24);
    *(short8*)(sdstA + 0)  = st0;
    *(short8*)(sdstA + 8)  = st1;
    *(short8*)(sdstA + 16) = st2;
    *(short8*)(sdstA + 24) = st3;
    __syncthreads();
    for (int t = 0; t < 4; ++t) {
        if (t + 1 < 4) {                       // issue next tile's loads early
            st0 = *(const short8*)(hsrc + (t + 1) * 128 + 0);
            st1 = *(const short8*)(hsrc + (t + 1) * 128 + 8);
            st2 = *(const short8*)(hsrc + (t + 1) * 128 + 16);
            st3 = *(const short8*)(hsrc + (t + 1) * 128 + 24);
        }
#pragma unroll
        for (int kk = 0; kk < 4; ++kk) {
            short8 a[4], b[4];
#pragma unroll
            for (int rf = 0; rf < 4; ++rf)
                a[rf] = *(const short8*)(ard[rf] + kk * 32);
#pragma unroll
            for (int cf = 0; cf < 4; ++cf)
                b[cf] = *(const short8*)(bp[cf] + t * 128 + kk * 32);
#pragma unroll
            for (int rf = 0; rf < 4; ++rf)
#pragma unroll
                for (int cf = 0; cf < 4; ++cf)
                    acc[rf][cf] = __builtin_amdgcn_mfma_f32_16x16x32_bf16(a[rf], b[cf], acc[rf][cf], 0, 0, 0);
        }
        __syncthreads();                       // all reads of Alds done
        if (t + 1 < 4) {
            *(short8*)(sdstA + 0)  = st0;
            *(short8*)(sdstA + 8)  = st1;
            *(short8*)(sdstA + 16) = st2;
            *(short8*)(sdstA + 24) = st3;
            __syncthreads();                   // writes visible
        }
    }

    // ================= phase B: x @ Wst, 4 tiles of BK=64 (R10-proven) =================
    {
        float4 f0 = *(const float4*)(xsrc + 0);
        float4 f1 = *(const float4*)(xsrc + 4);
        float4 f2 = *(const float4*)(xsrc + 8);
        float4 f3 = *(const float4*)(xsrc + 12);
        union { short8 s; unsigned u[4]; } p0, p1;
        p0.u[0] = cvt_pk_bf16(f0.x, f0.y); p0.u[1] = cvt_pk_bf16(f0.z, f0.w);
        p0.u[2] = cvt_pk_bf16(f1.x, f1.y); p0.u[3] = cvt_pk_bf16(f1.z, f1.w);
        p1.u[0] = cvt_pk_bf16(f2.x, f2.y); p1.u[1] = cvt_pk_bf16(f2.z, f2.w);
        p1.u[2] = cvt_pk_bf16(f3.x, f3.y); p1.u[3] = cvt_pk_bf16(f3.z, f3.w);
        *(short8*)sdstB0 = p0.s;
        *(short8*)sdstB1 = p1.s;
    }
    __syncthreads();
    for (int t = 0; t < 4; ++t) {
        float4 f0, f1, f2, f3;
        if (t + 1 < 4) {
            f0 = *(const float4*)(xsrc + (t + 1) * 64);
            f1 = *(const float4*)(xsrc + (t + 1) * 64 + 4);
            f2 = *(const float4*)(xsrc + (t + 1) * 64 + 8);
            f3 = *(const float4*)(xsrc + (t + 1) * 64 + 12);
        }
#pragma unroll
        for (int kk = 0; kk < 2; ++kk) {
            short8 a[4], b[4];
#pragma unroll
            for (int rf = 0; rf < 4; ++rf)
                a[rf] = *(const short8*)(ard[rf] + kk * 32);
#pragma unroll
            for (int cf = 0; cf < 4; ++cf)
                b[cf] = *(const short8*)(sp[cf] + t * 64 + kk * 32);
#pragma unroll
            for (int rf = 0; rf < 4; ++rf)
#pragma unroll
                for (int cf = 0; cf < 4; ++cf)
                    acc[rf][cf] = __builtin_amdgcn_mfma_f32_16x16x32_bf16(a[rf], b[cf], acc[rf][cf], 0, 0, 0);
        }
        __syncthreads();
        if (t + 1 < 4) {
            union { short8 s; unsigned u[4]; } p0, p1;
            p0.u[0] = cvt_pk_bf16(f0.x, f0.y); p0.u[1] = cvt_pk_bf16(f0.z, f0.w);
            p0.u[2] = cvt_pk_bf16(f1.x, f1.y); p0.u[3] = cvt_pk_bf16(f1.z, f1.w);
            p1.u[0] = cvt_pk_bf16(f2.x, f2.y); p1.u[1] = cvt_pk_bf16(f2.z, f2.w);
            p1.u[2] = cvt_pk_bf16(f3.x, f3.y); p1.u[3] = cvt_pk_bf16(f3.z, f3.w);
            *(short8*)sdstB0 = p0.s;
            *(short8*)sdstB1 = p1.s;
            __syncthreads();
        }
    }

    // epilogue: + deg*b2 + bs, LayerNorm over 256 cols, ReLU
    float b2v[4], bsv[4], gv[4], bv[4];
#pragma unroll
    for (int cf = 0; cf < 4; ++cf) {
        int col = colw + 16 * cf + l15;
        b2v[cf] = b2[col]; bsv[cf] = bs[col]; gv[cf] = gamma[col]; bv[cf] = beta[col];
    }
#pragma unroll
    for (int rf = 0; rf < 4; ++rf) {
#pragma unroll
        for (int r = 0; r < 4; ++r) {
            int row = 16 * rf + 4 * lg + r;
            float dg = sdeg[row];
            float s = 0.f, sq = 0.f;
#pragma unroll
            for (int cf = 0; cf < 4; ++cf) {
                float v = acc[rf][cf][r] + dg * b2v[cf] + bsv[cf];
                acc[rf][cf][r] = v;
                s += v; sq += v * v;
            }
#pragma unroll
            for (int o = 8; o > 0; o >>= 1) {
                s  += __shfl_xor(s, o);
                sq += __shfl_xor(sq, o);
            }
            if (l15 == 0) { sred[w][row] = s; sqred[w][row] = sq; }
        }
    }
    __syncthreads();
#pragma unroll
    for (int rf = 0; rf < 4; ++rf) {
#pragma unroll
        for (int r = 0; r < 4; ++r) {
            int row = 16 * rf + 4 * lg + r;
            int g = row0 + row;
            if (g >= N) continue;
            float tot  = sred[0][row] + sred[1][row] + sred[2][row] + sred[3][row];
            float totq = sqred[0][row] + sqred[1][row] + sqred[2][row] + sqred[3][row];
            float mu = tot * (1.f / OUT_CHN);
            float var = totq * (1.f / OUT_CHN) - mu * mu;
            float rstd = rsqrtf(var + 1e-5f);
#pragma unroll
            for (int cf = 0; cf < 4; ++cf) {
                int col = colw + 16 * cf + l15;
                float v = (acc[rf][cf][r] - mu) * rstd * gv[cf] + bv[cf];
                out[(size_t)g * OUT_CHN + col] = fmaxf(v, 0.f);
            }
        }
    }
}

extern "C" void kernel_launch(void* const* d_in, const int* in_sizes, int n_in,
                              void* d_out, int out_size, void* d_ws, size_t ws_size,
                              hipStream_t stream)
{
    const float* x     = (const float*)d_in[0];
    const int*   ei    = (const int*)d_in[1];
    const int*   etype = (const int*)d_in[2];
    const float* rel   = (const float*)d_in[3];
    const float* W1    = (const float*)d_in[4];
    const float* b1    = (const float*)d_in[5];
    const float* W2    = (const float*)d_in[6];
    const float* b2    = (const float*)d_in[7];
    const float* Ws    = (const float*)d_in[8];
    const float* bs    = (const float*)d_in[9];
    const float* gamma = (const float*)d_in[10];
    const float* beta  = (const float*)d_in[11];

    const int N  = in_sizes[0] / IN_CHN;
    const int E  = in_sizes[2];
    const int NR = in_sizes[3] / REL_DIM;
    float* outp = (float*)d_out;

    char* wsp = (char*)d_ws;
    auto carve = [&](size_t bytes) { char* p = wsp; wsp += (bytes + 255) & ~(size_t)255; return p; };
    unsigned short* X1  = (unsigned short*)carve((size_t)N * HIDN * 2);
    unsigned short* Rb  = (unsigned short*)carve((size_t)NR * HIDN * 2);
    unsigned short* Bt  = (unsigned short*)carve((size_t)HIDN * IN_CHN * 2);
    unsigned short* W2t = (unsigned short*)carve((size_t)OUT_CHN * HIDN * 2);
    unsigned short* Wst = (unsigned short*)carve((size_t)OUT_CHN * IN_CHN * 2);
    int* offs  = (int*)carve(((size_t)N + 1) * 4);
    int* cnt   = (int*)carve((size_t)N * 4);
    int* bsum  = (int*)carve(512 * 4);
    int* eperm = (int*)carve((size_t)E * 4);

    // Hagg (bf16, N x 512 = out_size*4 bytes) lives in d_out; k_out overwrites in place.
    unsigned short* Hagg = (unsigned short*)d_out;

    hipMemsetAsync(cnt, 0, (size_t)N * 4, stream);

    const int prep_total = HIDN * IN_CHN + OUT_CHN * HIDN + OUT_CHN * IN_CHN;
    k_prep_w<<<dim3((prep_total + 255) / 256), dim3(256), 0, stream>>>(W1, Ws, W2, Bt, W2t, Wst);
    k_rel<<<dim3(NR), dim3(512), 0, stream>>>(rel, W1, b1, Rb);
    k_node<<<dim3((N + 63) / 64), dim3(512), 0, stream>>>(x, Bt, X1, N);
    k_hist<<<dim3((E + 255) / 256), dim3(256), 0, stream>>>(ei, cnt, E);
    int NB = (N + 511) / 512;
    k_scan1<<<dim3(NB), dim3(512), 0, stream>>>(cnt, offs, bsum, N);
    k_scan2<<<dim3(1), dim3(512), 0, stream>>>(bsum, NB);
    k_scan3<<<dim3((N + 255) / 256), dim3(256), 0, stream>>>(offs, bsum, cnt, N, E);
    k_scatter<<<dim3((E + 255) / 256), dim3(256), 0, stream>>>(ei, etype, cnt, eperm, E);
    k_gather<<<dim3((N + 3) / 4), dim3(256), 0, stream>>>(offs, eperm, X1, Rb, Hagg, N);
    k_out<<<dim3((N + 63) / 64), dim3(256), 0, stream>>>(Hagg, W2t, Wst, x, offs,
                                                         b2, bs, gamma, beta, outp, N);
}

// Round 18
// 412.700 us; speedup vs baseline: 1.0311x; 1.0311x over previous
//
#include <hip/hip_runtime.h>
#include <hip/hip_bf16.h>

#define IN_CHN 256
#define OUT_CHN 256
#define REL_DIM 1536
#define HIDN 512

using short8 = __attribute__((ext_vector_type(8))) short;
using f32x4  = __attribute__((ext_vector_type(4))) float;

__device__ __forceinline__ float bf2f(short s) {
    union { unsigned u; float f; } v;
    v.u = ((unsigned)(unsigned short)s) << 16;
    return v.f;
}
__device__ __forceinline__ unsigned cvt_pk_bf16(float a, float b) {
    unsigned r;
    asm("v_cvt_pk_bf16_f32 %0, %1, %2" : "=v"(r) : "v"(a), "v"(b));
    return r;
}
__device__ __forceinline__ unsigned short f2bf_s(float f) {
    union { float f; unsigned u; } v; v.f = f;
    unsigned u = v.u + 0x7FFFu + ((v.u >> 16) & 1u);
    return (unsigned short)(u >> 16);
}

// ---------------- prep: transpose+cast weights to bf16 ----------------
__global__ void k_prep_w(const float* __restrict__ W1, const float* __restrict__ Ws,
                         const float* __restrict__ W2,
                         unsigned short* __restrict__ Bt, unsigned short* __restrict__ W2t,
                         unsigned short* __restrict__ Wst)
{
    int idx = blockIdx.x * 256 + threadIdx.x;
    const int n1 = HIDN * IN_CHN;
    const int n2 = OUT_CHN * HIDN;
    const int n3 = OUT_CHN * IN_CHN;
    if (idx < n1) {
        int j = idx >> 8, k = idx & 255;
        Bt[idx] = f2bf_s(W1[(size_t)k * HIDN + j]);
    } else if (idx < n1 + n2) {
        int t = idx - n1;
        int j = t >> 9, k = t & 511;
        W2t[t] = f2bf_s(W2[(size_t)k * OUT_CHN + j]);
    } else if (idx < n1 + n2 + n3) {
        int t = idx - n1 - n2;
        int j = t >> 8, k = t & 255;
        Wst[t] = f2bf_s(Ws[(size_t)k * OUT_CHN + j]);
    }
}

// ---------------- R[r] = rel[r] @ W1_bot + b1 (bf16 out) ----------------
__global__ __launch_bounds__(512) void k_rel(const float* __restrict__ rel,
                                             const float* __restrict__ W1,
                                             const float* __restrict__ b1,
                                             unsigned short* __restrict__ Rb)
{
    __shared__ float s[REL_DIM];
    const int r = blockIdx.x;
    for (int i = threadIdx.x; i < REL_DIM; i += 512)
        s[i] = rel[(size_t)r * REL_DIM + i];
    __syncthreads();
    const int j = threadIdx.x;
    float acc = b1[j];
    const float* wp = W1 + (size_t)IN_CHN * HIDN + j;
#pragma unroll 8
    for (int k = 0; k < REL_DIM; ++k)
        acc = fmaf(s[k], wp[(size_t)k * HIDN], acc);
    Rb[r * HIDN + j] = f2bf_s(acc);
}

// ---------------- node GEMM: X1 = bf16(x) @ Bt^T  (R10-proven body) ----------------
// grid (ceil(N/64), 2); block 256 (4 waves x 64 cols = 256 cols per y-block).
__global__ __launch_bounds__(256) void k_node(const float* __restrict__ x,
                                              const unsigned short* __restrict__ Bt,
                                              unsigned short* __restrict__ X1, int N)
{
    __shared__ unsigned short Alds[64][72];   // 9.2 KB, +8-short pad
    const int row0 = blockIdx.x * 64;
    const int colb = blockIdx.y * 256;
    const int tid = threadIdx.x;
    const int w = tid >> 6, l = tid & 63;
    const int l15 = l & 15, lg = l >> 4;
    const int colw = colb + w * 64;

    // staging role: thread t covers row t>>2, 16 f32 elements at (t&3)*16
    const int srow = tid >> 2;
    int srowg = row0 + srow; if (srowg >= N) srowg = N - 1;
    const int sc = (tid & 3) * 16;
    const float* xsrc = x + (size_t)srowg * IN_CHN + sc;
    unsigned short* sdst0 = &Alds[srow][sc];
    unsigned short* sdst1 = &Alds[srow][sc + 8];

    const unsigned short* bp[4];
#pragma unroll
    for (int cf = 0; cf < 4; ++cf)
        bp[cf] = Bt + (size_t)(colw + 16 * cf + l15) * IN_CHN + 8 * lg;
    const unsigned short* ard[4];
#pragma unroll
    for (int rf = 0; rf < 4; ++rf)
        ard[rf] = &Alds[16 * rf + l15][lg * 8];

    f32x4 acc[4][4] = {};

    {   // stage tile 0
        float4 f0 = *(const float4*)(xsrc + 0);
        float4 f1 = *(const float4*)(xsrc + 4);
        float4 f2 = *(const float4*)(xsrc + 8);
        float4 f3 = *(const float4*)(xsrc + 12);
        union { short8 s; unsigned u[4]; } p0, p1;
        p0.u[0] = cvt_pk_bf16(f0.x, f0.y); p0.u[1] = cvt_pk_bf16(f0.z, f0.w);
        p0.u[2] = cvt_pk_bf16(f1.x, f1.y); p0.u[3] = cvt_pk_bf16(f1.z, f1.w);
        p1.u[0] = cvt_pk_bf16(f2.x, f2.y); p1.u[1] = cvt_pk_bf16(f2.z, f2.w);
        p1.u[2] = cvt_pk_bf16(f3.x, f3.y); p1.u[3] = cvt_pk_bf16(f3.z, f3.w);
        *(short8*)sdst0 = p0.s;
        *(short8*)sdst1 = p1.s;
    }
    __syncthreads();
    for (int t = 0; t < 4; ++t) {             // K=256 as 4 tiles of BK=64
        float4 f0, f1, f2, f3;
        if (t + 1 < 4) {                      // issue next tile's loads early
            f0 = *(const float4*)(xsrc + (t + 1) * 64);
            f1 = *(const float4*)(xsrc + (t + 1) * 64 + 4);
            f2 = *(const float4*)(xsrc + (t + 1) * 64 + 8);
            f3 = *(const float4*)(xsrc + (t + 1) * 64 + 12);
        }
#pragma unroll
        for (int kk = 0; kk < 2; ++kk) {
            short8 a[4], b[4];
#pragma unroll
            for (int rf = 0; rf < 4; ++rf)
                a[rf] = *(const short8*)(ard[rf] + kk * 32);
#pragma unroll
            for (int cf = 0; cf < 4; ++cf)
                b[cf] = *(const short8*)(bp[cf] + t * 64 + kk * 32);
#pragma unroll
            for (int rf = 0; rf < 4; ++rf)
#pragma unroll
                for (int cf = 0; cf < 4; ++cf)
                    acc[rf][cf] = __builtin_amdgcn_mfma_f32_16x16x32_bf16(a[rf], b[cf], acc[rf][cf], 0, 0, 0);
        }
        __syncthreads();
        if (t + 1 < 4) {
            union { short8 s; unsigned u[4]; } p0, p1;
            p0.u[0] = cvt_pk_bf16(f0.x, f0.y); p0.u[1] = cvt_pk_bf16(f0.z, f0.w);
            p0.u[2] = cvt_pk_bf16(f1.x, f1.y); p0.u[3] = cvt_pk_bf16(f1.z, f1.w);
            p1.u[0] = cvt_pk_bf16(f2.x, f2.y); p1.u[1] = cvt_pk_bf16(f2.z, f2.w);
            p1.u[2] = cvt_pk_bf16(f3.x, f3.y); p1.u[3] = cvt_pk_bf16(f3.z, f3.w);
            *(short8*)sdst0 = p0.s;
            *(short8*)sdst1 = p1.s;
            __syncthreads();
        }
    }

#pragma unroll
    for (int rf = 0; rf < 4; ++rf) {
#pragma unroll
        for (int cf = 0; cf < 4; ++cf) {
            int col = colw + 16 * cf + l15;
#pragma unroll
            for (int r = 0; r < 4; ++r) {
                int row = row0 + 16 * rf + 4 * lg + r;
                if (row >= N) continue;
                X1[(size_t)row * HIDN + col] = f2bf_s(acc[rf][cf][r]);
            }
        }
    }
}

// ---------------- CSR build ----------------
__global__ void k_hist(const int* __restrict__ ei, int* __restrict__ cnt, int E)
{
    int e = blockIdx.x * 256 + threadIdx.x;
    if (e < E) atomicAdd(&cnt[ei[E + e]], 1);
}

__global__ __launch_bounds__(512) void k_scan1(const int* __restrict__ cnt, int* __restrict__ offs,
                                               int* __restrict__ bsum, int N)
{
    __shared__ int s[512];
    int t = threadIdx.x;
    int i = blockIdx.x * 512 + t;
    int v = (i < N) ? cnt[i] : 0;
    s[t] = v;
    __syncthreads();
    for (int d = 1; d < 512; d <<= 1) {
        int a = (t >= d) ? s[t - d] : 0;
        __syncthreads();
        s[t] += a;
        __syncthreads();
    }
    if (i < N) offs[i] = s[t] - v;
    if (t == 511) bsum[blockIdx.x] = s[511];
}

__global__ __launch_bounds__(512) void k_scan2(int* __restrict__ bsum, int NB)
{
    __shared__ int s[512];
    int t = threadIdx.x;
    if (t < NB) s[t] = bsum[t];
    __syncthreads();
    if (t == 0) {
        int run = 0;
        for (int j = 0; j < NB; ++j) { int v = s[j]; s[j] = run; run += v; }
    }
    __syncthreads();
    if (t < NB) bsum[t] = s[t];
}

__global__ void k_scan3(int* __restrict__ offs, const int* __restrict__ bsum,
                        int* __restrict__ cursor, int N, int E)
{
    int i = blockIdx.x * 256 + threadIdx.x;
    if (i < N) {
        int v = offs[i] + bsum[i >> 9];
        offs[i] = v;
        cursor[i] = v;
    }
    if (i == 0) offs[N] = E;
}

__global__ void k_scatter(const int* __restrict__ ei, const int* __restrict__ et,
                          int* __restrict__ cursor, int* __restrict__ eperm, int E)
{
    int e = blockIdx.x * 256 + threadIdx.x;
    if (e < E) {
        int d = ei[E + e];
        int pos = atomicAdd(&cursor[d], 1);
        eperm[pos] = ei[e] | (et[e] << 20);   // src | etype<<20
    }
}

// ---------------- gather: Hagg[g] = sum_{e->g} relu(X1[src]+R[et]) (bf16, R6-proven) ----------------
__global__ __launch_bounds__(256, 6) void k_gather(const int* __restrict__ offs,
                                                   const int* __restrict__ eperm,
                                                   const unsigned short* __restrict__ X1,
                                                   const unsigned short* __restrict__ Rb,
                                                   unsigned short* __restrict__ Hagg, int N)
{
    const int g = (blockIdx.x * 256 + threadIdx.x) >> 6;   // global wave id = node
    const int l = threadIdx.x & 63;
    if (g >= N) return;
    const int o0 = offs[g], o1 = offs[g + 1];
    const int deg = o1 - o0;
    float a8[8] = {};
    for (int base = 0; base < deg; base += 64) {
        const int nk = min(64, deg - base);
        int pv = eperm[o0 + base + (l < nk ? l : nk - 1)];
        for (int e = 0; e < nk; e += 4) {
            int pvk[4];
#pragma unroll
            for (int k2 = 0; k2 < 4; ++k2)
                pvk[k2] = __shfl(pv, e + k2);
            short8 xa[4], ra[4];
#pragma unroll
            for (int k2 = 0; k2 < 4; ++k2) {
                if (e + k2 < nk) {
                    xa[k2] = *(const short8*)(X1 + (size_t)(pvk[k2] & 0xFFFFF) * HIDN + l * 8);
                    ra[k2] = *(const short8*)(Rb + (pvk[k2] >> 20) * HIDN + l * 8);
                }
            }
#pragma unroll
            for (int k2 = 0; k2 < 4; ++k2) {
                if (e + k2 < nk) {
#pragma unroll
                    for (int j = 0; j < 8; ++j)
                        a8[j] += fmaxf(bf2f(xa[k2][j]) + bf2f(ra[k2][j]), 0.f);
                }
            }
        }
    }
    union { short8 s; unsigned u[4]; } pk;
    pk.u[0] = cvt_pk_bf16(a8[0], a8[1]);
    pk.u[1] = cvt_pk_bf16(a8[2], a8[3]);
    pk.u[2] = cvt_pk_bf16(a8[4], a8[5]);
    pk.u[3] = cvt_pk_bf16(a8[6], a8[7]);
    *(short8*)(Hagg + (size_t)g * HIDN + l * 8) = pk.s;
}

// ---------------- out GEMM: out = Hagg@W2t + x@Wst + deg*b2 + bs -> LN -> ReLU ----------------
// R13-proven 64-row body: phase A = 4 tiles of BK=128, phase B = 4 tiles of BK=64.
// Row stride 136 shorts (proven bank signature). Hagg aliases d_out.
__global__ __launch_bounds__(256) void k_out(const unsigned short* __restrict__ Hagg,
                                             const unsigned short* __restrict__ W2t,
                                             const unsigned short* __restrict__ Wst,
                                             const float* __restrict__ x,
                                             const int* __restrict__ offs,
                                             const float* __restrict__ b2,
                                             const float* __restrict__ bs,
                                             const float* __restrict__ gamma,
                                             const float* __restrict__ beta,
                                             float* __restrict__ out, int N)
{
    __shared__ unsigned short Alds[64][136];  // 17.4 KB, +8-short pad
    __shared__ float sdeg[64];
    __shared__ float sred[4][64], sqred[4][64];
    const int row0 = blockIdx.x * 64;
    const int tid = threadIdx.x;
    const int w = tid >> 6, l = tid & 63;
    const int l15 = l & 15, lg = l >> 4;
    const int colw = w * 64;

    if (tid < 64) {
        int g = row0 + tid;
        if (g >= N) g = N - 1;
        sdeg[tid] = (float)(offs[g + 1] - offs[g]);
    }

    const int srow = tid >> 2;
    int srowg = row0 + srow; if (srowg >= N) srowg = N - 1;
    // phase A staging: 32 shorts/thread at (t&3)*32
    const int scA = (tid & 3) * 32;
    const unsigned short* hsrc = Hagg + (size_t)srowg * HIDN + scA;
    unsigned short* sdstA = &Alds[srow][scA];
    // phase B staging: 16 shorts/thread at (t&3)*16 (R10 pattern)
    const int scB = (tid & 3) * 16;
    const float* xsrc = x + (size_t)srowg * IN_CHN + scB;
    unsigned short* sdstB0 = &Alds[srow][scB];
    unsigned short* sdstB1 = &Alds[srow][scB + 8];

    const unsigned short* bp[4];
    const unsigned short* sp[4];
#pragma unroll
    for (int cf = 0; cf < 4; ++cf) {
        bp[cf] = W2t + (size_t)(colw + 16 * cf + l15) * HIDN + 8 * lg;
        sp[cf] = Wst + (size_t)(colw + 16 * cf + l15) * IN_CHN + 8 * lg;
    }
    const unsigned short* ard[4];
#pragma unroll
    for (int rf = 0; rf < 4; ++rf)
        ard[rf] = &Alds[16 * rf + l15][lg * 8];

    f32x4 acc[4][4] = {};
    short8 st0, st1, st2, st3;

    // ================= phase A: Hagg @ W2t, 4 tiles of BK=128 =================
    st0 = *(const short8*)(hsrc + 0);
    st1 = *(const short8*)(hsrc + 8);
    st2 = *(const short8*)(hsrc + 16);
    st3 = *(const short8*)(hsrc + 24);
    *(short8*)(sdstA + 0)  = st0;
    *(short8*)(sdstA + 8)  = st1;
    *(short8*)(sdstA + 16) = st2;
    *(short8*)(sdstA + 24) = st3;
    __syncthreads();
    for (int t = 0; t < 4; ++t) {
        if (t + 1 < 4) {                       // issue next tile's loads early
            st0 = *(const short8*)(hsrc + (t + 1) * 128 + 0);
            st1 = *(const short8*)(hsrc + (t + 1) * 128 + 8);
            st2 = *(const short8*)(hsrc + (t + 1) * 128 + 16);
            st3 = *(const short8*)(hsrc + (t + 1) * 128 + 24);
        }
#pragma unroll
        for (int kk = 0; kk < 4; ++kk) {
            short8 a[4], b[4];
#pragma unroll
            for (int rf = 0; rf < 4; ++rf)
                a[rf] = *(const short8*)(ard[rf] + kk * 32);
#pragma unroll
            for (int cf = 0; cf < 4; ++cf)
                b[cf] = *(const short8*)(bp[cf] + t * 128 + kk * 32);
#pragma unroll
            for (int rf = 0; rf < 4; ++rf)
#pragma unroll
                for (int cf = 0; cf < 4; ++cf)
                    acc[rf][cf] = __builtin_amdgcn_mfma_f32_16x16x32_bf16(a[rf], b[cf], acc[rf][cf], 0, 0, 0);
        }
        __syncthreads();                       // all reads of Alds done
        if (t + 1 < 4) {
            *(short8*)(sdstA + 0)  = st0;
            *(short8*)(sdstA + 8)  = st1;
            *(short8*)(sdstA + 16) = st2;
            *(short8*)(sdstA + 24) = st3;
            __syncthreads();                   // writes visible
        }
    }

    // ================= phase B: x @ Wst, 4 tiles of BK=64 (R10-proven) =================
    {
        float4 f0 = *(const float4*)(xsrc + 0);
        float4 f1 = *(const float4*)(xsrc + 4);
        float4 f2 = *(const float4*)(xsrc + 8);
        float4 f3 = *(const float4*)(xsrc + 12);
        union { short8 s; unsigned u[4]; } p0, p1;
        p0.u[0] = cvt_pk_bf16(f0.x, f0.y); p0.u[1] = cvt_pk_bf16(f0.z, f0.w);
        p0.u[2] = cvt_pk_bf16(f1.x, f1.y); p0.u[3] = cvt_pk_bf16(f1.z, f1.w);
        p1.u[0] = cvt_pk_bf16(f2.x, f2.y); p1.u[1] = cvt_pk_bf16(f2.z, f2.w);
        p1.u[2] = cvt_pk_bf16(f3.x, f3.y); p1.u[3] = cvt_pk_bf16(f3.z, f3.w);
        *(short8*)sdstB0 = p0.s;
        *(short8*)sdstB1 = p1.s;
    }
    __syncthreads();
    for (int t = 0; t < 4; ++t) {
        float4 f0, f1, f2, f3;
        if (t + 1 < 4) {
            f0 = *(const float4*)(xsrc + (t + 1) * 64);
            f1 = *(const float4*)(xsrc + (t + 1) * 64 + 4);
            f2 = *(const float4*)(xsrc + (t + 1) * 64 + 8);
            f3 = *(const float4*)(xsrc + (t + 1) * 64 + 12);
        }
#pragma unroll
        for (int kk = 0; kk < 2; ++kk) {
            short8 a[4], b[4];
#pragma unroll
            for (int rf = 0; rf < 4; ++rf)
                a[rf] = *(const short8*)(ard[rf] + kk * 32);
#pragma unroll
            for (int cf = 0; cf < 4; ++cf)
                b[cf] = *(const short8*)(sp[cf] + t * 64 + kk * 32);
#pragma unroll
            for (int rf = 0; rf < 4; ++rf)
#pragma unroll
                for (int cf = 0; cf < 4; ++cf)
                    acc[rf][cf] = __builtin_amdgcn_mfma_f32_16x16x32_bf16(a[rf], b[cf], acc[rf][cf], 0, 0, 0);
        }
        __syncthreads();
        if (t + 1 < 4) {
            union { short8 s; unsigned u[4]; } p0, p1;
            p0.u[0] = cvt_pk_bf16(f0.x, f0.y); p0.u[1] = cvt_pk_bf16(f0.z, f0.w);
            p0.u[2] = cvt_pk_bf16(f1.x, f1.y); p0.u[3] = cvt_pk_bf16(f1.z, f1.w);
            p1.u[0] = cvt_pk_bf16(f2.x, f2.y); p1.u[1] = cvt_pk_bf16(f2.z, f2.w);
            p1.u[2] = cvt_pk_bf16(f3.x, f3.y); p1.u[3] = cvt_pk_bf16(f3.z, f3.w);
            *(short8*)sdstB0 = p0.s;
            *(short8*)sdstB1 = p1.s;
            __syncthreads();
        }
    }

    // epilogue: + deg*b2 + bs, LayerNorm over 256 cols, ReLU
    float b2v[4], bsv[4], gv[4], bv[4];
#pragma unroll
    for (int cf = 0; cf < 4; ++cf) {
        int col = colw + 16 * cf + l15;
        b2v[cf] = b2[col]; bsv[cf] = bs[col]; gv[cf] = gamma[col]; bv[cf] = beta[col];
    }
#pragma unroll
    for (int rf = 0; rf < 4; ++rf) {
#pragma unroll
        for (int r = 0; r < 4; ++r) {
            int row = 16 * rf + 4 * lg + r;
            float dg = sdeg[row];
            float s = 0.f, sq = 0.f;
#pragma unroll
            for (int cf = 0; cf < 4; ++cf) {
                float v = acc[rf][cf][r] + dg * b2v[cf] + bsv[cf];
                acc[rf][cf][r] = v;
                s += v; sq += v * v;
            }
#pragma unroll
            for (int o = 8; o > 0; o >>= 1) {
                s  += __shfl_xor(s, o);
                sq += __shfl_xor(sq, o);
            }
            if (l15 == 0) { sred[w][row] = s; sqred[w][row] = sq; }
        }
    }
    __syncthreads();
#pragma unroll
    for (int rf = 0; rf < 4; ++rf) {
#pragma unroll
        for (int r = 0; r < 4; ++r) {
            int row = 16 * rf + 4 * lg + r;
            int g = row0 + row;
            if (g >= N) continue;
            float tot  = sred[0][row] + sred[1][row] + sred[2][row] + sred[3][row];
            float totq = sqred[0][row] + sqred[1][row] + sqred[2][row] + sqred[3][row];
            float mu = tot * (1.f / OUT_CHN);
            float var = totq * (1.f / OUT_CHN) - mu * mu;
            float rstd = rsqrtf(var + 1e-5f);
#pragma unroll
            for (int cf = 0; cf < 4; ++cf) {
                int col = colw + 16 * cf + l15;
                float v = (acc[rf][cf][r] - mu) * rstd * gv[cf] + bv[cf];
                out[(size_t)g * OUT_CHN + col] = fmaxf(v, 0.f);
            }
        }
    }
}

extern "C" void kernel_launch(void* const* d_in, const int* in_sizes, int n_in,
                              void* d_out, int out_size, void* d_ws, size_t ws_size,
                              hipStream_t stream)
{
    const float* x     = (const float*)d_in[0];
    const int*   ei    = (const int*)d_in[1];
    const int*   etype = (const int*)d_in[2];
    const float* rel   = (const float*)d_in[3];
    const float* W1    = (const float*)d_in[4];
    const float* b1    = (const float*)d_in[5];
    const float* W2    = (const float*)d_in[6];
    const float* b2    = (const float*)d_in[7];
    const float* Ws    = (const float*)d_in[8];
    const float* bs    = (const float*)d_in[9];
    const float* gamma = (const float*)d_in[10];
    const float* beta  = (const float*)d_in[11];

    const int N  = in_sizes[0] / IN_CHN;
    const int E  = in_sizes[2];
    const int NR = in_sizes[3] / REL_DIM;
    float* outp = (float*)d_out;

    char* wsp = (char*)d_ws;
    auto carve = [&](size_t bytes) { char* p = wsp; wsp += (bytes + 255) & ~(size_t)255; return p; };
    unsigned short* X1  = (unsigned short*)carve((size_t)N * HIDN * 2);
    unsigned short* Rb  = (unsigned short*)carve((size_t)NR * HIDN * 2);
    unsigned short* Bt  = (unsigned short*)carve((size_t)HIDN * IN_CHN * 2);
    unsigned short* W2t = (unsigned short*)carve((size_t)OUT_CHN * HIDN * 2);
    unsigned short* Wst = (unsigned short*)carve((size_t)OUT_CHN * IN_CHN * 2);
    int* offs  = (int*)carve(((size_t)N + 1) * 4);
    int* cnt   = (int*)carve((size_t)N * 4);
    int* bsum  = (int*)carve(512 * 4);
    int* eperm = (int*)carve((size_t)E * 4);

    // Hagg (bf16, N x 512 = out_size*4 bytes) lives in d_out; k_out overwrites in place.
    unsigned short* Hagg = (unsigned short*)d_out;

    hipMemsetAsync(cnt, 0, (size_t)N * 4, stream);

    const int prep_total = HIDN * IN_CHN + OUT_CHN * HIDN + OUT_CHN * IN_CHN;
    k_prep_w<<<dim3((prep_total + 255) / 256), dim3(256), 0, stream>>>(W1, Ws, W2, Bt, W2t, Wst);
    k_rel<<<dim3(NR), dim3(512), 0, stream>>>(rel, W1, b1, Rb);
    k_node<<<dim3((N + 63) / 64, 2), dim3(256), 0, stream>>>(x, Bt, X1, N);
    k_hist<<<dim3((E + 255) / 256), dim3(256), 0, stream>>>(ei, cnt, E);
    int NB = (N + 511) / 512;
    k_scan1<<<dim3(NB), dim3(512), 0, stream>>>(cnt, offs, bsum, N);
    k_scan2<<<dim3(1), dim3(512), 0, stream>>>(bsum, NB);
    k_scan3<<<dim3((N + 255) / 256), dim3(256), 0, stream>>>(offs, bsum, cnt, N, E);
    k_scatter<<<dim3((E + 255) / 256), dim3(256), 0, stream>>>(ei, etype, cnt, eperm, E);
    k_gather<<<dim3((N + 3) / 4), dim3(256), 0, stream>>>(offs, eperm, X1, Rb, Hagg, N);
    k_out<<<dim3((N + 63) / 64), dim3(256), 0, stream>>>(Hagg, W2t, Wst, x, offs,
                                                         b2, bs, gamma, beta, outp, N);
}